// Round 1
// baseline (4043.481 us; speedup 1.0000x reference)
//
#include <hip/hip_runtime.h>

// NSDE Monte-Carlo pricer: 512 paths x 64 options x 32 steps, 4 MLPs [4->64->64->1].
// Mapping: block = path (512 blocks), lane = option (64), 2 waves/block split the
// 2 independent nets of each phase. Weights are wave-uniform -> s_load + SGPR
// operands on v_fmac (no LDS in hot loop). 1024 waves = 1 wave/SIMD on MI355X.

#define N_PATHS 512
#define N_STEPS 32
#define B_OPTS  64
#define HID     64

__device__ __forceinline__ float fast_tanh(float x) {
    // tanh(x) = 1 - 2/(e^{2x}+1); exp2-based, correct saturation at +/-inf.
    float u = __builtin_amdgcn_exp2f(x * 2.8853900817779268f); // e^{2x}
    float r = __builtin_amdgcn_rcpf(u + 1.0f);
    return fmaf(-2.0f, r, 1.0f);
}

__device__ __forceinline__ float mlp4(
    float x0, float x1, float x2, float x3,
    const float* __restrict__ W0, const float* __restrict__ b0,
    const float* __restrict__ W1, const float* __restrict__ b1,
    const float* __restrict__ W2, float b2v)
{
    float h1[HID];
#pragma unroll
    for (int j = 0; j < HID; ++j) {
        float a = b0[j];
        a = fmaf(x0, W0[0*HID + j], a);
        a = fmaf(x1, W0[1*HID + j], a);
        a = fmaf(x2, W0[2*HID + j], a);
        a = fmaf(x3, W0[3*HID + j], a);
        h1[j] = fast_tanh(a);
    }
    float h2[HID];
#pragma unroll
    for (int j = 0; j < HID; ++j) h2[j] = b1[j];
    // k-outer / j-inner: weight row W1[k][:] is 256B contiguous -> s_load_dwordx16
#pragma unroll 4
    for (int k = 0; k < HID; ++k) {
        float a = h1[k];
        const float* __restrict__ w = &W1[k * HID];
#pragma unroll
        for (int j = 0; j < HID; ++j) h2[j] = fmaf(a, w[j], h2[j]);
    }
    float acc0 = b2v, acc1 = 0.0f, acc2 = 0.0f, acc3 = 0.0f;
#pragma unroll
    for (int j = 0; j < HID; j += 4) {
        acc0 = fmaf(fast_tanh(h2[j + 0]), W2[j + 0], acc0);
        acc1 = fmaf(fast_tanh(h2[j + 1]), W2[j + 1], acc1);
        acc2 = fmaf(fast_tanh(h2[j + 2]), W2[j + 2], acc2);
        acc3 = fmaf(fast_tanh(h2[j + 3]), W2[j + 3], acc3);
    }
    return (acc0 + acc1) + (acc2 + acc3);
}

__global__ __launch_bounds__(128) void nsde_kernel(
    const float* __restrict__ S0p, const float* __restrict__ Kp,
    const float* __restrict__ Tp,  const float* __restrict__ rfp,
    const float* __restrict__ Z1,  const float* __restrict__ Z2,
    const float* __restrict__ W0,  const float* __restrict__ b0,
    const float* __restrict__ W1,  const float* __restrict__ b1,
    const float* __restrict__ W2,  const float* __restrict__ b2,
    float* __restrict__ out)
{
    const int path = blockIdx.x;          // 512 blocks = 512 paths
    const int wave = threadIdx.x >> 6;    // 0 or 1
    const int o    = threadIdx.x & 63;    // option index

    __shared__ float lds_f[2][B_OPTS];

    const float rf   = rfp[0];
    const float Topt = Tp[o];
    const float dt   = Topt * (1.0f / (float)N_STEPS);
    const float sqdt = sqrtf(dt);
    float S = S0p[o];
    float V = 0.2f;

    const int netA = wave;       // phase-1 net: 0 or 1
    const int netB = 2 + wave;   // phase-2 net: 2 or 3
    const float* __restrict__ W0A = W0 + netA * 4 * HID;
    const float* __restrict__ b0A = b0 + netA * HID;
    const float* __restrict__ W1A = W1 + netA * HID * HID;
    const float* __restrict__ b1A = b1 + netA * HID;
    const float* __restrict__ W2A = W2 + netA * HID;
    const float               b2A = b2[netA];
    const float* __restrict__ W0B = W0 + netB * 4 * HID;
    const float* __restrict__ b0B = b0 + netB * HID;
    const float* __restrict__ W1B = W1 + netB * HID * HID;
    const float* __restrict__ b1B = b1 + netB * HID;
    const float* __restrict__ W2B = W2 + netB * HID;
    const float               b2B = b2[netB];

    for (int j = 0; j < N_STEPS; ++j) {
        const float z1 = Z1[path * N_STEPS + j];   // wave-uniform -> s_load
        const float z2 = Z2[path * N_STEPS + j];
        const float t  = dt * (float)j;

        // Phase 1: nets 0 (wave0) and 1 (wave1) on input [S, V, rf, t]
        float f = mlp4(S, V, rf, t, W0A, b0A, W1A, b1A, W2A, b2A);
        lds_f[wave][o] = f;
        __syncthreads();
        const float f0 = lds_f[0][o];
        const float f1 = lds_f[1][o];
        __syncthreads();                 // reads done before slots are rewritten
        S = S * (1.0f + f0 * dt + f1 * z1);

        // Phase 2: nets 2/3 on input [S_new, V, rf, t]
        float g = mlp4(S, V, rf, t, W0B, b0B, W1B, b1B, W2B, b2B);
        lds_f[wave][o] = g;
        __syncthreads();
        const float g0 = lds_f[0][o];
        const float g1 = lds_f[1][o];
        __syncthreads();
        V = V * (1.0f + g0 * dt + g1 * sqdt * z2);
    }

    if (wave == 0) {
        const float pay  = (S - Kp[o] < 0.0f) ? 0.0f : S;   // where(S-K<0, 0, S)
        const float disc = __builtin_amdgcn_exp2f(-rf * Topt * 1.44269504f)
                           * (1.0f / (float)N_PATHS);
        atomicAdd(&out[o], pay * disc);
    }
}

__global__ void zero_out_kernel(float* __restrict__ out) {
    out[threadIdx.x] = 0.0f;
}

extern "C" void kernel_launch(void* const* d_in, const int* in_sizes, int n_in,
                              void* d_out, int out_size, void* d_ws, size_t ws_size,
                              hipStream_t stream) {
    const float* S0p = (const float*)d_in[0];
    const float* Kp  = (const float*)d_in[1];
    const float* Tp  = (const float*)d_in[2];
    const float* rfp = (const float*)d_in[3];
    const float* Z1  = (const float*)d_in[4];
    const float* Z2  = (const float*)d_in[5];
    const float* W0  = (const float*)d_in[6];
    const float* b0  = (const float*)d_in[7];
    const float* W1  = (const float*)d_in[8];
    const float* b1  = (const float*)d_in[9];
    const float* W2  = (const float*)d_in[10];
    const float* b2  = (const float*)d_in[11];
    float* out = (float*)d_out;

    zero_out_kernel<<<1, B_OPTS, 0, stream>>>(out);
    nsde_kernel<<<N_PATHS, 128, 0, stream>>>(S0p, Kp, Tp, rfp, Z1, Z2,
                                             W0, b0, W1, b1, W2, b2, out);
}

// Round 2
// 2423.237 us; speedup vs baseline: 1.6686x; 1.6686x over previous
//
#include <hip/hip_runtime.h>

// NSDE Monte-Carlo pricer: 512 paths x 64 options x 32 steps, 4 MLPs [4->64->64->1].
// Mapping: block = path (512 blocks), lane = option (64), 2 waves/block split the
// 2 independent nets of each phase. 1024 waves = 1 wave/SIMD on MI355X.
//
// R2: round-1 kernel spilled (FETCH 2.85GB / WRITE 1.19GB of scratch traffic,
// VGPR=256 cap). Fix: fuse layer-1 into the k-loop (kills h1[64] array),
// explicit float4 weight loads, __launch_bounds__(128,1) for the 512-VGPR
// budget (we run 1 wave/SIMD regardless).

#define N_PATHS 512
#define N_STEPS 32
#define B_OPTS  64
#define HID     64

__device__ __forceinline__ float fast_tanh(float x) {
    // tanh(x) = 1 - 2/(e^{2x}+1); exp2-based, correct saturation at +/-inf.
    float u = __builtin_amdgcn_exp2f(x * 2.8853900817779268f); // e^{2x}
    float r = __builtin_amdgcn_rcpf(u + 1.0f);
    return fmaf(-2.0f, r, 1.0f);
}

__device__ __forceinline__ float mlp4_fused(
    float x0, float x1, float x2, float x3,
    const float* __restrict__ W0n, const float* __restrict__ b0n,
    const float* __restrict__ W1n, const float* __restrict__ b1n,
    const float* __restrict__ W2n, float b2v)
{
    float acc[HID];
#pragma unroll
    for (int j = 0; j < HID; ++j) acc[j] = b1n[j];

    // Layer 1 fused into layer-2 accumulation: h1[k] is computed on demand
    // (1 live register), then fanned out into 64 accumulators via the 256B
    // contiguous W1 row (16 float4 loads).
#pragma unroll 2
    for (int k = 0; k < HID; ++k) {
        float a = b0n[k];
        a = fmaf(x0, W0n[0 * HID + k], a);
        a = fmaf(x1, W0n[1 * HID + k], a);
        a = fmaf(x2, W0n[2 * HID + k], a);
        a = fmaf(x3, W0n[3 * HID + k], a);
        const float h = fast_tanh(a);
        const float4* __restrict__ w =
            reinterpret_cast<const float4*>(W1n + k * HID);
#pragma unroll
        for (int q = 0; q < HID / 4; ++q) {
            const float4 wv = w[q];
            acc[4 * q + 0] = fmaf(h, wv.x, acc[4 * q + 0]);
            acc[4 * q + 1] = fmaf(h, wv.y, acc[4 * q + 1]);
            acc[4 * q + 2] = fmaf(h, wv.z, acc[4 * q + 2]);
            acc[4 * q + 3] = fmaf(h, wv.w, acc[4 * q + 3]);
        }
    }

    float s0 = b2v, s1 = 0.0f, s2 = 0.0f, s3 = 0.0f;
#pragma unroll
    for (int j = 0; j < HID; j += 4) {
        s0 = fmaf(fast_tanh(acc[j + 0]), W2n[j + 0], s0);
        s1 = fmaf(fast_tanh(acc[j + 1]), W2n[j + 1], s1);
        s2 = fmaf(fast_tanh(acc[j + 2]), W2n[j + 2], s2);
        s3 = fmaf(fast_tanh(acc[j + 3]), W2n[j + 3], s3);
    }
    return (s0 + s1) + (s2 + s3);
}

__global__ __launch_bounds__(128, 1) void nsde_kernel(
    const float* __restrict__ S0p, const float* __restrict__ Kp,
    const float* __restrict__ Tp,  const float* __restrict__ rfp,
    const float* __restrict__ Z1,  const float* __restrict__ Z2,
    const float* __restrict__ W0,  const float* __restrict__ b0,
    const float* __restrict__ W1,  const float* __restrict__ b1,
    const float* __restrict__ W2,  const float* __restrict__ b2,
    float* __restrict__ out)
{
    const int path = blockIdx.x;          // 512 blocks = 512 paths
    const int wave = threadIdx.x >> 6;    // 0 or 1
    const int o    = threadIdx.x & 63;    // option index

    __shared__ float lds_f[2][B_OPTS];

    const float rf   = rfp[0];
    const float Topt = Tp[o];
    const float dt   = Topt * (1.0f / (float)N_STEPS);
    const float sqdt = sqrtf(dt);
    float S = S0p[o];
    float V = 0.2f;

    const int netA = wave;       // phase-1 net: 0 or 1
    const int netB = 2 + wave;   // phase-2 net: 2 or 3
    const float* __restrict__ W0A = W0 + netA * 4 * HID;
    const float* __restrict__ b0A = b0 + netA * HID;
    const float* __restrict__ W1A = W1 + netA * HID * HID;
    const float* __restrict__ b1A = b1 + netA * HID;
    const float* __restrict__ W2A = W2 + netA * HID;
    const float               b2A = b2[netA];
    const float* __restrict__ W0B = W0 + netB * 4 * HID;
    const float* __restrict__ b0B = b0 + netB * HID;
    const float* __restrict__ W1B = W1 + netB * HID * HID;
    const float* __restrict__ b1B = b1 + netB * HID;
    const float* __restrict__ W2B = W2 + netB * HID;
    const float               b2B = b2[netB];

    for (int j = 0; j < N_STEPS; ++j) {
        const float z1 = Z1[path * N_STEPS + j];   // wave-uniform
        const float z2 = Z2[path * N_STEPS + j];
        const float t  = dt * (float)j;

        // Phase 1: nets 0 (wave0) and 1 (wave1) on input [S, V, rf, t]
        float f = mlp4_fused(S, V, rf, t, W0A, b0A, W1A, b1A, W2A, b2A);
        lds_f[wave][o] = f;
        __syncthreads();
        const float f0 = lds_f[0][o];
        const float f1 = lds_f[1][o];
        __syncthreads();                 // reads done before slots are rewritten
        S = S * (1.0f + f0 * dt + f1 * z1);

        // Phase 2: nets 2/3 on input [S_new, V, rf, t]
        float g = mlp4_fused(S, V, rf, t, W0B, b0B, W1B, b1B, W2B, b2B);
        lds_f[wave][o] = g;
        __syncthreads();
        const float g0 = lds_f[0][o];
        const float g1 = lds_f[1][o];
        __syncthreads();
        V = V * (1.0f + g0 * dt + g1 * sqdt * z2);
    }

    if (wave == 0) {
        const float pay  = (S - Kp[o] < 0.0f) ? 0.0f : S;   // where(S-K<0, 0, S)
        const float disc = __builtin_amdgcn_exp2f(-rf * Topt * 1.44269504f)
                           * (1.0f / (float)N_PATHS);
        atomicAdd(&out[o], pay * disc);
    }
}

__global__ void zero_out_kernel(float* __restrict__ out) {
    out[threadIdx.x] = 0.0f;
}

extern "C" void kernel_launch(void* const* d_in, const int* in_sizes, int n_in,
                              void* d_out, int out_size, void* d_ws, size_t ws_size,
                              hipStream_t stream) {
    const float* S0p = (const float*)d_in[0];
    const float* Kp  = (const float*)d_in[1];
    const float* Tp  = (const float*)d_in[2];
    const float* rfp = (const float*)d_in[3];
    const float* Z1  = (const float*)d_in[4];
    const float* Z2  = (const float*)d_in[5];
    const float* W0  = (const float*)d_in[6];
    const float* b0  = (const float*)d_in[7];
    const float* W1  = (const float*)d_in[8];
    const float* b1  = (const float*)d_in[9];
    const float* W2  = (const float*)d_in[10];
    const float* b2  = (const float*)d_in[11];
    float* out = (float*)d_out;

    zero_out_kernel<<<1, B_OPTS, 0, stream>>>(out);
    nsde_kernel<<<N_PATHS, 128, 0, stream>>>(S0p, Kp, Tp, rfp, Z1, Z2,
                                             W0, b0, W1, b1, W2, b2, out);
}

// Round 3
// 829.620 us; speedup vs baseline: 4.8739x; 2.9209x over previous
//
#include <hip/hip_runtime.h>

// NSDE Monte-Carlo pricer: 512 paths x 64 options x 32 steps, 4 MLPs [4->64->64->1].
// Mapping: block = path (512 blocks), lane = option (64), 2 waves/block split the
// 2 independent nets of each phase. 1024 waves = 1 wave/SIMD on MI355X.
//
// R2 fixed spilling (fused layer-1, FETCH 2.85GB->488KB) but left VALUBusy at
// 16%: weight reads compiled to vector global loads; at 1 wave/SIMD each
// k-iteration ate ~1400 cyc of vmcnt latency (~200 cyc L1/L2 hit, poorly
// pipelined). R3: stage all weights in LDS once per block (72.8 KB, still
// 2 blocks/CU), hot loop uses broadcast ds_read_b128 on the DS pipe which
// overlaps VALU and pipelines via lgkmcnt. W0 transposed to [k][4] at staging.

#define N_PATHS 512
#define N_STEPS 32
#define B_OPTS  64
#define HID     64

// Per-net LDS layout (floats). Stride padded to 4548 (18192 B, 16B-aligned).
//   [   0, 256)  W0T  : transposed [k=64][d=4]
//   [ 256, 320)  b0   : [64]
//   [ 320,4416)  W1   : [64][64] row-major
//   [4416,4480)  b1   : [64]
//   [4480,4544)  W2   : [64]
//   [4544]       b2
#define NET_STRIDE 4548
#define OFF_W0T 0
#define OFF_B0  256
#define OFF_W1  320
#define OFF_B1  4416
#define OFF_W2  4480
#define OFF_B2  4544

__device__ __forceinline__ float fast_tanh(float x) {
    // tanh(x) = 1 - 2/(e^{2x}+1); exp2-based, correct saturation at +/-inf.
    float u = __builtin_amdgcn_exp2f(x * 2.8853900817779268f); // e^{2x}
    float r = __builtin_amdgcn_rcpf(u + 1.0f);
    return fmaf(-2.0f, r, 1.0f);
}

// One MLP [4->64->64->1], all weights read from LDS (wave-uniform -> broadcast).
__device__ __forceinline__ float mlp4_lds(
    float x0, float x1, float x2, float x3, const float* __restrict__ nb)
{
    float acc[HID];
    const float4* __restrict__ b1v =
        reinterpret_cast<const float4*>(nb + OFF_B1);
#pragma unroll
    for (int q = 0; q < HID / 4; ++q) {
        const float4 b = b1v[q];
        acc[4 * q + 0] = b.x; acc[4 * q + 1] = b.y;
        acc[4 * q + 2] = b.z; acc[4 * q + 3] = b.w;
    }

    const float4* __restrict__ w0t =
        reinterpret_cast<const float4*>(nb + OFF_W0T);
#pragma unroll 2
    for (int k = 0; k < HID; ++k) {
        const float4 w0 = w0t[k];            // ds_read_b128 (broadcast)
        float a = nb[OFF_B0 + k];            // ds_read_b32
        a = fmaf(x0, w0.x, a);
        a = fmaf(x1, w0.y, a);
        a = fmaf(x2, w0.z, a);
        a = fmaf(x3, w0.w, a);
        const float h = fast_tanh(a);
        const float4* __restrict__ w =
            reinterpret_cast<const float4*>(nb + OFF_W1 + k * HID);
#pragma unroll
        for (int q = 0; q < HID / 4; ++q) {
            const float4 wv = w[q];          // ds_read_b128 (broadcast)
            acc[4 * q + 0] = fmaf(h, wv.x, acc[4 * q + 0]);
            acc[4 * q + 1] = fmaf(h, wv.y, acc[4 * q + 1]);
            acc[4 * q + 2] = fmaf(h, wv.z, acc[4 * q + 2]);
            acc[4 * q + 3] = fmaf(h, wv.w, acc[4 * q + 3]);
        }
    }

    const float* __restrict__ W2n = nb + OFF_W2;
    float s0 = nb[OFF_B2], s1 = 0.0f, s2 = 0.0f, s3 = 0.0f;
#pragma unroll
    for (int j = 0; j < HID; j += 4) {
        s0 = fmaf(fast_tanh(acc[j + 0]), W2n[j + 0], s0);
        s1 = fmaf(fast_tanh(acc[j + 1]), W2n[j + 1], s1);
        s2 = fmaf(fast_tanh(acc[j + 2]), W2n[j + 2], s2);
        s3 = fmaf(fast_tanh(acc[j + 3]), W2n[j + 3], s3);
    }
    return (s0 + s1) + (s2 + s3);
}

__global__ __launch_bounds__(128, 1) void nsde_kernel(
    const float* __restrict__ S0p, const float* __restrict__ Kp,
    const float* __restrict__ Tp,  const float* __restrict__ rfp,
    const float* __restrict__ Z1,  const float* __restrict__ Z2,
    const float* __restrict__ W0,  const float* __restrict__ b0,
    const float* __restrict__ W1,  const float* __restrict__ b1,
    const float* __restrict__ W2,  const float* __restrict__ b2,
    float* __restrict__ out)
{
    const int path = blockIdx.x;          // 512 blocks = 512 paths
    const int tid  = threadIdx.x;
    const int wave = tid >> 6;            // 0 or 1
    const int o    = tid & 63;            // option index

    __shared__ float wsm[4 * NET_STRIDE]; // 72768 B -> 2 blocks/CU
    __shared__ float lds_f[2][B_OPTS];

    // ---- Stage all 4 nets' weights into LDS (once per block) ----
    {
        const float4* __restrict__ W1v = reinterpret_cast<const float4*>(W1);
        for (int i = tid; i < 4096; i += 128) {          // W1: 16384 floats
            const int net = i >> 10, idx = i & 1023;
            *reinterpret_cast<float4*>(&wsm[net * NET_STRIDE + OFF_W1 + 4 * idx])
                = W1v[i];
        }
        for (int i = tid; i < 1024; i += 128) {          // W0 (4,4,64) -> W0T [k][d]
            const int net = i >> 8, r = i & 255, d = r >> 6, k = r & 63;
            wsm[net * NET_STRIDE + OFF_W0T + k * 4 + d] = W0[i];
        }
        for (int i = tid; i < 256; i += 128) {           // b0 (4,64)
            wsm[(i >> 6) * NET_STRIDE + OFF_B0 + (i & 63)] = b0[i];
        }
        for (int i = tid; i < 256; i += 128) {           // b1 (4,64)
            wsm[(i >> 6) * NET_STRIDE + OFF_B1 + (i & 63)] = b1[i];
        }
        for (int i = tid; i < 256; i += 128) {           // W2 (4,64,1)
            wsm[(i >> 6) * NET_STRIDE + OFF_W2 + (i & 63)] = W2[i];
        }
        if (tid < 4) wsm[tid * NET_STRIDE + OFF_B2] = b2[tid];
    }
    __syncthreads();

    const float rf   = rfp[0];
    const float Topt = Tp[o];
    const float dt   = Topt * (1.0f / (float)N_STEPS);
    const float sqdt = sqrtf(dt);
    float S = S0p[o];
    float V = 0.2f;

    const float* __restrict__ nbA = &wsm[wave * NET_STRIDE];        // net 0/1
    const float* __restrict__ nbB = &wsm[(2 + wave) * NET_STRIDE];  // net 2/3

    for (int j = 0; j < N_STEPS; ++j) {
        const float z1 = Z1[path * N_STEPS + j];   // wave-uniform
        const float z2 = Z2[path * N_STEPS + j];
        const float t  = dt * (float)j;

        // Phase 1: nets 0 (wave0) and 1 (wave1) on input [S, V, rf, t]
        const float f = mlp4_lds(S, V, rf, t, nbA);
        lds_f[wave][o] = f;
        __syncthreads();
        const float f0 = lds_f[0][o];
        const float f1 = lds_f[1][o];
        __syncthreads();                 // reads done before slots are rewritten
        S = S * (1.0f + f0 * dt + f1 * z1);

        // Phase 2: nets 2/3 on input [S_new, V, rf, t]
        const float g = mlp4_lds(S, V, rf, t, nbB);
        lds_f[wave][o] = g;
        __syncthreads();
        const float g0 = lds_f[0][o];
        const float g1 = lds_f[1][o];
        __syncthreads();
        V = V * (1.0f + g0 * dt + g1 * sqdt * z2);
    }

    if (wave == 0) {
        const float pay  = (S - Kp[o] < 0.0f) ? 0.0f : S;   // where(S-K<0, 0, S)
        const float disc = __builtin_amdgcn_exp2f(-rf * Topt * 1.44269504f)
                           * (1.0f / (float)N_PATHS);
        atomicAdd(&out[o], pay * disc);
    }
}

__global__ void zero_out_kernel(float* __restrict__ out) {
    out[threadIdx.x] = 0.0f;
}

extern "C" void kernel_launch(void* const* d_in, const int* in_sizes, int n_in,
                              void* d_out, int out_size, void* d_ws, size_t ws_size,
                              hipStream_t stream) {
    const float* S0p = (const float*)d_in[0];
    const float* Kp  = (const float*)d_in[1];
    const float* Tp  = (const float*)d_in[2];
    const float* rfp = (const float*)d_in[3];
    const float* Z1  = (const float*)d_in[4];
    const float* Z2  = (const float*)d_in[5];
    const float* W0  = (const float*)d_in[6];
    const float* b0  = (const float*)d_in[7];
    const float* W1  = (const float*)d_in[8];
    const float* b1  = (const float*)d_in[9];
    const float* W2  = (const float*)d_in[10];
    const float* b2  = (const float*)d_in[11];
    float* out = (float*)d_out;

    zero_out_kernel<<<1, B_OPTS, 0, stream>>>(out);
    nsde_kernel<<<N_PATHS, 128, 0, stream>>>(S0p, Kp, Tp, rfp, Z1, Z2,
                                             W0, b0, W1, b1, W2, b2, out);
}

// Round 4
// 336.504 us; speedup vs baseline: 12.0161x; 2.4654x over previous
//
#include <hip/hip_runtime.h>

// NSDE pricer, R4: MFMA restructure.
// 32768 rows (path*64+opt). Wave = 32 rows (2 M-tiles of 16), block = 256 thr
// = 4 waves = 2 paths, grid = 256 -> 1024 waves = 1/SIMD (512-VGPR budget).
// Layer2 (64x64) per net = 16x mfma_f32_16x16x32_bf16; W1 resident as bf16
// B-frags in 128 VGPRs. Layer1/3 + tanh in fp32 VALU. S,V in per-wave LDS
// slices -> no __syncthreads in the 32-step loop. Only h1 and W1 are bf16.

#define N_PATHS 512
#define N_STEPS 32
#define B_OPTS  64
#define HID     64

typedef __attribute__((ext_vector_type(8))) short bf16x8;   // 8 bf16 (4 VGPRs)
typedef __attribute__((ext_vector_type(4))) float f32x4;

__device__ __forceinline__ float fast_tanh(float x) {
    // tanh(x) = 1 - 2/(e^{2x}+1); exp2-based, correct saturation at +/-inf.
    float u = __builtin_amdgcn_exp2f(x * 2.8853900817779268f);
    float r = __builtin_amdgcn_rcpf(u + 1.0f);
    return fmaf(-2.0f, r, 1.0f);
}

__device__ __forceinline__ short f2bf(float f) {            // fp32 -> bf16 RNE
    union { float f; unsigned u; } c; c.f = f;
    unsigned u = c.u + 0x7FFFu + ((c.u >> 16) & 1u);
    return (short)(u >> 16);
}

__device__ __forceinline__ float select4(float a0, float a1, float a2, float a3, int idx) {
    float lo = (idx & 1) ? a1 : a0;
    float hi = (idx & 1) ? a3 : a2;
    return (idx & 2) ? hi : lo;
}

// Two nets of one phase: layer1 (VALU, A-layout), layer2 (MFMA), layer3+tanh.
// fout[nn][t][reg] = f for rows (16t + 4q + reg) of this wave, all lanes valid.
__device__ __forceinline__ void mlp_pair(
    int base, int q, int nh,
    float Sa0, float Sa1, float Va0, float Va1, float tA0, float tA1,
    const float4* __restrict__ w0t4,            // LDS, [4][72] swizzled
    const bf16x8 (&bfr)[4][4][2],
    const float (&b1v)[4][4], const float (&w2v)[4][4], const float (&b2s)[4],
    float (&fout)[2][2][4])
{
#pragma unroll
    for (int nn = 0; nn < 2; ++nn) {
        const int net = base + nn;
        // ---- layer1 in A-fragment layout: lane holds h1[row=16t+nh][k=32kh+8q+j]
        bf16x8 afr[2][2];                        // [t][kh]
#pragma unroll
        for (int kh = 0; kh < 2; ++kh) {
#pragma unroll
            for (int j = 0; j < 8; ++j) {
                const int kk = kh * 32 + q * 8 + j;
                const float4 w = w0t4[net * 72 + kk + (kk >> 3)]; // bank-swizzled
                {
                    float a = fmaf(Sa0, w.x, fmaf(Va0, w.y, fmaf(tA0, w.z, w.w)));
                    afr[0][kh][j] = f2bf(fast_tanh(a));
                }
                {
                    float a = fmaf(Sa1, w.x, fmaf(Va1, w.y, fmaf(tA1, w.z, w.w)));
                    afr[1][kh][j] = f2bf(fast_tanh(a));
                }
            }
        }
        // ---- layer2: 2 M-tiles x 4 N-tiles x 2 K-halves
        f32x4 C[2][4];
#pragma unroll
        for (int t = 0; t < 2; ++t) {
#pragma unroll
            for (int nt = 0; nt < 4; ++nt) {
                f32x4 c = {0.0f, 0.0f, 0.0f, 0.0f};
                c = __builtin_amdgcn_mfma_f32_16x16x32_bf16(afr[t][0], bfr[net][nt][0], c, 0, 0, 0);
                c = __builtin_amdgcn_mfma_f32_16x16x32_bf16(afr[t][1], bfr[net][nt][1], c, 0, 0, 0);
                C[t][nt] = c;
            }
        }
        // ---- layer3: tanh, dot with W2 over nt, reduce over 16 C-columns
#pragma unroll
        for (int t = 0; t < 2; ++t) {
#pragma unroll
            for (int reg = 0; reg < 4; ++reg) {
                float s = 0.0f;
#pragma unroll
                for (int nt = 0; nt < 4; ++nt)
                    s = fmaf(fast_tanh(C[t][nt][reg] + b1v[net][nt]), w2v[net][nt], s);
                s += __shfl_xor(s, 1);
                s += __shfl_xor(s, 2);
                s += __shfl_xor(s, 4);
                s += __shfl_xor(s, 8);
                fout[nn][t][reg] = s + b2s[net];
            }
        }
    }
}

__global__ __launch_bounds__(256, 1) void nsde_kernel(
    const float* __restrict__ S0p, const float* __restrict__ Kp,
    const float* __restrict__ Tp,  const float* __restrict__ rfp,
    const float* __restrict__ Z1,  const float* __restrict__ Z2,
    const float* __restrict__ W0,  const float* __restrict__ b0,
    const float* __restrict__ W1,  const float* __restrict__ b1,
    const float* __restrict__ W2,  const float* __restrict__ b2,
    float* __restrict__ out, float* __restrict__ ws, int use_ws)
{
    const int tid  = threadIdx.x;
    const int wave = tid >> 6;
    const int lane = tid & 63;
    const int q    = lane >> 4;
    const int nh   = lane & 15;
    const int blk  = blockIdx.x;
    const int path = blk * 2 + (wave >> 1);         // uniform per wave

    __shared__ float  S_lds[128], V_lds[128];
    __shared__ float4 w0t4[4 * 72];                 // swizzled (w_S,w_V,w_t, b0+rf*w_rf)

    const float rf = rfp[0];

    // ---- one-time staging ----
    if (tid < 256) {
        const int net = tid >> 6, kk = tid & 63;
        const float wsv = W0[net * 256 + 0 * 64 + kk];
        const float wvv = W0[net * 256 + 1 * 64 + kk];
        const float wrv = W0[net * 256 + 2 * 64 + kk];
        const float wtv = W0[net * 256 + 3 * 64 + kk];
        w0t4[net * 72 + kk + (kk >> 3)] =
            make_float4(wsv, wvv, wtv, fmaf(rf, wrv, b0[net * 64 + kk]));
    }
    if (tid < 128) { S_lds[tid] = S0p[tid & 63]; V_lds[tid] = 0.2f; }

    // ---- per-lane constants ----
    const int lA0 = wave * 32 + nh;                 // A-layout local rows
    const int lA1 = lA0 + 16;
    const int lW0 = wave * 32 + 4 * q + (nh & 3);   // writer local rows
    const int lW1 = lW0 + 16;
    const float dta0 = Tp[lA0 & 63] * (1.0f / N_STEPS);
    const float dta1 = Tp[lA1 & 63] * (1.0f / N_STEPS);
    const float dtw0 = Tp[lW0 & 63] * (1.0f / N_STEPS);
    const float dtw1 = Tp[lW1 & 63] * (1.0f / N_STEPS);
    const float sqw0 = sqrtf(dtw0);
    const float sqw1 = sqrtf(dtw1);

    float b1v[4][4], w2v[4][4], b2s[4];
#pragma unroll
    for (int net = 0; net < 4; ++net) {
        b2s[net] = b2[net];
#pragma unroll
        for (int nt = 0; nt < 4; ++nt) {
            b1v[net][nt] = b1[net * 64 + nt * 16 + nh];
            w2v[net][nt] = W2[net * 64 + nt * 16 + nh];
        }
    }

    // ---- W1 -> resident bf16 B-fragments: B[k=32kh+8q+j][n=16nt+nh] ----
    bf16x8 bfr[4][4][2];
#pragma unroll
    for (int net = 0; net < 4; ++net)
#pragma unroll
        for (int nt = 0; nt < 4; ++nt)
#pragma unroll
            for (int kh = 0; kh < 2; ++kh)
#pragma unroll
                for (int j = 0; j < 8; ++j)
                    bfr[net][nt][kh][j] = f2bf(
                        W1[net * 4096 + (kh * 32 + q * 8 + j) * 64 + nt * 16 + nh]);

    __syncthreads();

    const float* __restrict__ z1p = Z1 + path * N_STEPS;
    const float* __restrict__ z2p = Z2 + path * N_STEPS;

    for (int step = 0; step < N_STEPS; ++step) {
        const float z1 = z1p[step];
        const float z2 = z2p[step];
        const float fs = (float)step;
        const float tA0 = dta0 * fs, tA1 = dta1 * fs;

        // ---- phase 1: nets 0,1 on (S, V, rf, t) ----
        float Sa0 = S_lds[lA0], Sa1 = S_lds[lA1];
        float Va0 = V_lds[lA0], Va1 = V_lds[lA1];
        float f[2][2][4];
        mlp_pair(0, q, nh, Sa0, Sa1, Va0, Va1, tA0, tA1,
                 w0t4, bfr, b1v, w2v, b2s, f);

        {   // S update, writer lanes nh<4 handle rows 16t+4q+nh
            const int r = nh & 3;
            const float f00 = select4(f[0][0][0], f[0][0][1], f[0][0][2], f[0][0][3], r);
            const float f10 = select4(f[1][0][0], f[1][0][1], f[1][0][2], f[1][0][3], r);
            const float f01 = select4(f[0][1][0], f[0][1][1], f[0][1][2], f[0][1][3], r);
            const float f11 = select4(f[1][1][0], f[1][1][1], f[1][1][2], f[1][1][3], r);
            const float Sn0 = S_lds[lW0] * fmaf(f10, z1, fmaf(f00, dtw0, 1.0f));
            const float Sn1 = S_lds[lW1] * fmaf(f11, z1, fmaf(f01, dtw1, 1.0f));
            if (nh < 4) { S_lds[lW0] = Sn0; S_lds[lW1] = Sn1; }
        }

        // ---- phase 2: nets 2,3 on (S_new, V, rf, t) ----
        Sa0 = S_lds[lA0]; Sa1 = S_lds[lA1];                 // updated S, same wave
        float g[2][2][4];
        mlp_pair(2, q, nh, Sa0, Sa1, Va0, Va1, tA0, tA1,
                 w0t4, bfr, b1v, w2v, b2s, g);

        {
            const int r = nh & 3;
            const float g00 = select4(g[0][0][0], g[0][0][1], g[0][0][2], g[0][0][3], r);
            const float g10 = select4(g[1][0][0], g[1][0][1], g[1][0][2], g[1][0][3], r);
            const float g01 = select4(g[0][1][0], g[0][1][1], g[0][1][2], g[0][1][3], r);
            const float g11 = select4(g[1][1][0], g[1][1][1], g[1][1][2], g[1][1][3], r);
            const float Vn0 = V_lds[lW0] * fmaf(g10, sqw0 * z2, fmaf(g00, dtw0, 1.0f));
            const float Vn1 = V_lds[lW1] * fmaf(g11, sqw1 * z2, fmaf(g01, dtw1, 1.0f));
            if (nh < 4) { V_lds[lW0] = Vn0; V_lds[lW1] = Vn1; }
        }
    }

    // ---- payoff: block partial per option ----
    __syncthreads();
    if (tid < 64) {
        const float Tt   = Tp[tid];
        const float disc = __builtin_amdgcn_exp2f(-rf * Tt * 1.4426950408889634f)
                           * (1.0f / (float)N_PATHS);
        const float Kv = Kp[tid];
        const float s1 = S_lds[tid],      s2 = S_lds[64 + tid];
        const float p1 = (s1 - Kv < 0.0f) ? 0.0f : s1;
        const float p2 = (s2 - Kv < 0.0f) ? 0.0f : s2;
        const float v  = disc * (p1 + p2);
        if (use_ws) ws[blk * 64 + tid] = v;
        else        atomicAdd(&out[tid], v);
    }
}

__global__ void reduce_kernel(const float* __restrict__ ws, float* __restrict__ out) {
    __shared__ float acc[4][64];
    const int o = threadIdx.x & 63, g = threadIdx.x >> 6;
    float s = 0.0f;
    for (int b = g; b < 256; b += 4) s += ws[b * 64 + o];
    acc[g][o] = s;
    __syncthreads();
    if (threadIdx.x < 64)
        out[threadIdx.x] = acc[0][threadIdx.x] + acc[1][threadIdx.x]
                         + acc[2][threadIdx.x] + acc[3][threadIdx.x];
}

__global__ void zero_out_kernel(float* __restrict__ out) {
    out[threadIdx.x] = 0.0f;
}

extern "C" void kernel_launch(void* const* d_in, const int* in_sizes, int n_in,
                              void* d_out, int out_size, void* d_ws, size_t ws_size,
                              hipStream_t stream) {
    const float* S0p = (const float*)d_in[0];
    const float* Kp  = (const float*)d_in[1];
    const float* Tp  = (const float*)d_in[2];
    const float* rfp = (const float*)d_in[3];
    const float* Z1  = (const float*)d_in[4];
    const float* Z2  = (const float*)d_in[5];
    const float* W0  = (const float*)d_in[6];
    const float* b0  = (const float*)d_in[7];
    const float* W1  = (const float*)d_in[8];
    const float* b1  = (const float*)d_in[9];
    const float* W2  = (const float*)d_in[10];
    const float* b2  = (const float*)d_in[11];
    float* out = (float*)d_out;
    float* wsf = (float*)d_ws;

    const int use_ws = (ws_size >= (size_t)(256 * 64 * sizeof(float))) ? 1 : 0;

    if (!use_ws) zero_out_kernel<<<1, B_OPTS, 0, stream>>>(out);
    nsde_kernel<<<256, 256, 0, stream>>>(S0p, Kp, Tp, rfp, Z1, Z2,
                                         W0, b0, W1, b1, W2, b2, out, wsf, use_ws);
    if (use_ws) reduce_kernel<<<1, 256, 0, stream>>>(wsf, out);
}